// Round 2
// baseline (694.898 us; speedup 1.0000x reference)
//
#include <hip/hip_runtime.h>

#define CHUNK 256
#define EMBD 256

typedef float fvec4 __attribute__((ext_vector_type(4)));

__global__ __launch_bounds__(256, 4)
void node_enc_kernel(const float* __restrict__ x,
                     const int* __restrict__ node_types,
                     const float* __restrict__ W0, const float* __restrict__ b0,
                     const float* __restrict__ E0_2, const float* __restrict__ E0_3,
                     const float* __restrict__ E0_5,
                     const float* __restrict__ W1, const float* __restrict__ b1,
                     const float* __restrict__ E1_2, const float* __restrict__ E1_3,
                     const float* __restrict__ W2, const float* __restrict__ b2,
                     const float* __restrict__ E2_0,
                     const float* __restrict__ W3, const float* __restrict__ b3,
                     const float* __restrict__ E3_0, const float* __restrict__ E3_1,
                     float* __restrict__ out, int n_nodes)
{
    __shared__ float xsh[CHUNK * 16];   // rows padded 14 -> 16 floats (b128-aligned)
    __shared__ int   tsh[CHUNK];

    const int tid = threadIdx.x;
    const int e   = tid;                 // output column owned by this thread
    const int n0  = blockIdx.x * CHUNK;
    const int chunk_n = min(CHUNK, n_nodes - n0);

    // ---- stage x rows + types into LDS (bulk, coalesced) ----
    {
        const float* src = x + (size_t)n0 * 14;   // n0 multiple of 256 -> 16B-aligned
        const int total = chunk_n * 14;
        const int nvec  = total >> 2;
        for (int i = tid; i < nvec; i += 256) {
            const fvec4 v = __builtin_nontemporal_load(reinterpret_cast<const fvec4*>(src) + i);
            int f    = i << 2;
            int node = f / 14;
            int col  = f - node * 14;
            #pragma unroll
            for (int j = 0; j < 4; ++j) {
                xsh[node * 16 + col] = v[j];
                ++col;
                if (col == 14) { col = 0; ++node; }
            }
        }
        for (int f = (nvec << 2) + tid; f < total; f += 256) {
            const int node = f / 14, col = f - node * 14;
            xsh[node * 16 + col] = src[f];
        }
        if (tid < chunk_n) tsh[tid] = node_types[n0 + tid];
    }

    // ---- per-column weights for all 4 types -> registers ----
    float w0[11], w1[12], w2[12], w3[12];
    #pragma unroll
    for (int k = 0; k < 11; ++k) w0[k] = W0[e * 11 + k];
    #pragma unroll
    for (int k = 0; k < 12; ++k) w1[k] = W1[e * 12 + k];
    #pragma unroll
    for (int k = 0; k < 12; ++k) w2[k] = W2[e * 12 + k];
    #pragma unroll
    for (int k = 0; k < 12; ++k) w3[k] = W3[e * 12 + k];
    const float bias0 = b0[e], bias1 = b1[e], bias2 = b2[e], bias3 = b3[e];

    // ---- per-thread embedding descriptors per type ----
    // type 0: [0,86)=E0_2 (stride 86, code col 2), [86,171)=E0_3 (85, col 3), [171,256)=E0_5 (85, col 5)
    int sc0, st0; const float* pbase0;
    if (e < 86)       { sc0 = 2; st0 = 86; pbase0 = E0_2 + e; }
    else if (e < 171) { sc0 = 3; st0 = 85; pbase0 = E0_3 + (e - 86); }
    else              { sc0 = 5; st0 = 85; pbase0 = E0_5 + (e - 171); }
    // type 1: [0,128)=E1_2 (128, col 2), [128,256)=E1_3 (128, col 3)
    int sc1, st1; const float* pbase1;
    if (e < 128) { sc1 = 2; st1 = 128; pbase1 = E1_2 + e; }
    else         { sc1 = 3; st1 = 128; pbase1 = E1_3 + (e - 128); }
    // type 2: [0,256)=E2_0 (256, col 0)
    const int sc2 = 0, st2 = 256; const float* pbase2 = E2_0 + e;
    // type 3: [0,128)=E3_0 (128, col 0), [128,256)=E3_1 (128, col 1)
    int sc3, st3; const float* pbase3;
    if (e < 128) { sc3 = 0; st3 = 128; pbase3 = E3_0 + e; }
    else         { sc3 = 1; st3 = 128; pbase3 = E3_1 + (e - 128); }

    __syncthreads();

    // branchless (uniform-select) embedding gather for node nl
    auto gather = [&](int nl) -> float {
        const int t = tsh[nl];
        const int sc = (t == 0) ? sc0 : (t == 1) ? sc1 : (t == 2) ? sc2 : sc3;
        const int st = (t == 0) ? st0 : (t == 1) ? st1 : (t == 2) ? st2 : st3;
        const float* pb = (t == 0) ? pbase0 : (t == 1) ? pbase1 : (t == 2) ? pbase2 : pbase3;
        const int code = (int)xsh[nl * 16 + sc];
        return pb[code * st];
    };

    float* const outp = out + (size_t)n0 * EMBD + e;

    // software pipeline the gathers 2 nodes ahead
    float embA = (chunk_n > 0) ? gather(0) : 0.f;
    float embB = (chunk_n > 1) ? gather(1) : 0.f;

    for (int nl = 0; nl < chunk_n; ++nl) {
        const float emb = embA;
        embA = embB;
        embB = (nl + 2 < chunk_n) ? gather(nl + 2) : 0.f;

        const float* xr = xsh + nl * 16;
        const float4 ra = *reinterpret_cast<const float4*>(xr);      // cols 0..3
        const float4 rb = *reinterpret_cast<const float4*>(xr + 4);  // cols 4..7
        const float4 rc = *reinterpret_cast<const float4*>(xr + 8);  // cols 8..11
        const float2 rd = *reinterpret_cast<const float2*>(xr + 12); // cols 12..13

        const int t = tsh[nl];
        float acc;
        if (t == 0) {
            // CONT0 = 0,1,4,6,7,8,9,10,11,12,13
            acc = fmaf(w0[0],  ra.x, bias0);
            acc = fmaf(w0[1],  ra.y, acc);
            acc = fmaf(w0[2],  rb.x, acc);
            acc = fmaf(w0[3],  rb.z, acc);
            acc = fmaf(w0[4],  rb.w, acc);
            acc = fmaf(w0[5],  rc.x, acc);
            acc = fmaf(w0[6],  rc.y, acc);
            acc = fmaf(w0[7],  rc.z, acc);
            acc = fmaf(w0[8],  rc.w, acc);
            acc = fmaf(w0[9],  rd.x, acc);
            acc = fmaf(w0[10], rd.y, acc);
        } else if (t == 1) {
            // CONT1 = 0,1,4,5,6,7,8,9,10,11,12,13
            acc = fmaf(w1[0],  ra.x, bias1);
            acc = fmaf(w1[1],  ra.y, acc);
            acc = fmaf(w1[2],  rb.x, acc);
            acc = fmaf(w1[3],  rb.y, acc);
            acc = fmaf(w1[4],  rb.z, acc);
            acc = fmaf(w1[5],  rb.w, acc);
            acc = fmaf(w1[6],  rc.x, acc);
            acc = fmaf(w1[7],  rc.y, acc);
            acc = fmaf(w1[8],  rc.z, acc);
            acc = fmaf(w1[9],  rc.w, acc);
            acc = fmaf(w1[10], rd.x, acc);
            acc = fmaf(w1[11], rd.y, acc);
        } else if (t == 2) {
            // CONT2 = 1,2,4,5,6,7,8,9,10,11,12,13
            acc = fmaf(w2[0],  ra.y, bias2);
            acc = fmaf(w2[1],  ra.z, acc);
            acc = fmaf(w2[2],  rb.x, acc);
            acc = fmaf(w2[3],  rb.y, acc);
            acc = fmaf(w2[4],  rb.z, acc);
            acc = fmaf(w2[5],  rb.w, acc);
            acc = fmaf(w2[6],  rc.x, acc);
            acc = fmaf(w2[7],  rc.y, acc);
            acc = fmaf(w2[8],  rc.z, acc);
            acc = fmaf(w2[9],  rc.w, acc);
            acc = fmaf(w2[10], rd.x, acc);
            acc = fmaf(w2[11], rd.y, acc);
        } else {
            // CONT3 = 2,3,4,5,6,7,8,9,10,11,12,13
            acc = fmaf(w3[0],  ra.z, bias3);
            acc = fmaf(w3[1],  ra.w, acc);
            acc = fmaf(w3[2],  rb.x, acc);
            acc = fmaf(w3[3],  rb.y, acc);
            acc = fmaf(w3[4],  rb.z, acc);
            acc = fmaf(w3[5],  rb.w, acc);
            acc = fmaf(w3[6],  rc.x, acc);
            acc = fmaf(w3[7],  rc.y, acc);
            acc = fmaf(w3[8],  rc.z, acc);
            acc = fmaf(w3[9],  rc.w, acc);
            acc = fmaf(w3[10], rd.x, acc);
            acc = fmaf(w3[11], rd.y, acc);
        }

        __builtin_nontemporal_store(acc + emb, outp + (size_t)nl * EMBD);
    }
}

extern "C" void kernel_launch(void* const* d_in, const int* in_sizes, int n_in,
                              void* d_out, int out_size, void* d_ws, size_t ws_size,
                              hipStream_t stream) {
    // setup_inputs() dict order:
    //  0:x  1:node_types  2:W0 3:b0 4:E0_2 5:E0_3 6:E0_5
    //  7:W1 8:b1 9:E1_2 10:E1_3  11:W2 12:b2 13:E2_0  14:W3 15:b3 16:E3_0 17:E3_1
    const float* xp   = (const float*)d_in[0];
    const int*   ntp  = (const int*)d_in[1];
    const float* W0 = (const float*)d_in[2];
    const float* b0 = (const float*)d_in[3];
    const float* E0_2 = (const float*)d_in[4];
    const float* E0_3 = (const float*)d_in[5];
    const float* E0_5 = (const float*)d_in[6];
    const float* W1 = (const float*)d_in[7];
    const float* b1 = (const float*)d_in[8];
    const float* E1_2 = (const float*)d_in[9];
    const float* E1_3 = (const float*)d_in[10];
    const float* W2 = (const float*)d_in[11];
    const float* b2 = (const float*)d_in[12];
    const float* E2_0 = (const float*)d_in[13];
    const float* W3 = (const float*)d_in[14];
    const float* b3 = (const float*)d_in[15];
    const float* E3_0 = (const float*)d_in[16];
    const float* E3_1 = (const float*)d_in[17];
    float* outp = (float*)d_out;

    const int n_nodes = in_sizes[1];
    const int grid = (n_nodes + CHUNK - 1) / CHUNK;
    node_enc_kernel<<<grid, 256, 0, stream>>>(
        xp, ntp, W0, b0, E0_2, E0_3, E0_5, W1, b1, E1_2, E1_3,
        W2, b2, E2_0, W3, b3, E3_0, E3_1, outp, n_nodes);
}